// Round 1
// baseline (222.568 us; speedup 1.0000x reference)
//
#include <hip/hip_runtime.h>
#include <hip/hip_bf16.h>
#include <stdint.h>

// B=4, T=1024, C=1024, H=16, D=64, ks=16
// wei[b,h,i,j] = cs[i][e(j)] - cs[i][s(j)], s=clip(j-16,0,64), e=clip(j+16,0,64)
// => wei==0 for j>=80; softmax tail folds into one weight * tail-sum of vp.
// R9: vp GEMM computes only the 128-row tiles actually read (j<80 per batch);
//     tails = (rowsum_{j>=80} v) @ Wv^T via vsum+tails kernels (no atomics in GEMM).
//     final_gemm rebuilt as 128x64 tiles (512 blocks, 2/CU) for 1.33x intensity.

typedef __bf16 bf16x8 __attribute__((ext_vector_type(8)));
typedef float f32x4 __attribute__((ext_vector_type(4)));

#define AS1(p) ((__attribute__((address_space(1))) void*)(p))
#define AS3(p) ((__attribute__((address_space(3))) void*)(p))

__device__ __forceinline__ float b2f(unsigned short h) {
  union { unsigned int u; float f; } x; x.u = ((unsigned int)h) << 16; return x.f;
}

// ---------------- fused fp32 -> bf16 convert (float4 per thread) ----------
// flat: idx<3M -> q,k,v (1M float4 each); else -> Wq,Wk,Wv,Wp (256K each).
// Block 16384 zeroes the 4096-float vsum buffer (consumer vsum_kernel is a
// later launch on the same stream).
__global__ __launch_bounds__(256) void cvt_kernel(
    const float* __restrict__ q, const float* __restrict__ k,
    const float* __restrict__ v, const float* __restrict__ Wq,
    const float* __restrict__ Wk, const float* __restrict__ Wv,
    const float* __restrict__ Wp,
    ushort4* __restrict__ qkv_bf, ushort4* __restrict__ w_bf,
    float* __restrict__ vsum)
{
  if (blockIdx.x == 16384) {
    float4* tz = (float4*)vsum;
    tz[threadIdx.x * 4 + 0] = make_float4(0.f, 0.f, 0.f, 0.f);
    tz[threadIdx.x * 4 + 1] = make_float4(0.f, 0.f, 0.f, 0.f);
    tz[threadIdx.x * 4 + 2] = make_float4(0.f, 0.f, 0.f, 0.f);
    tz[threadIdx.x * 4 + 3] = make_float4(0.f, 0.f, 0.f, 0.f);
    return;
  }
  int idx = blockIdx.x * 256 + threadIdx.x;
  const float* src; ushort4* dst; int i;
  if (idx < 3145728) {
    int which = idx >> 20; i = idx & 1048575;
    src = which == 0 ? q : which == 1 ? k : v;
    dst = qkv_bf + (size_t)which * 1048576 + i;
  } else {
    int w = idx - 3145728; int which = w >> 18; i = w & 262143;
    src = which == 0 ? Wq : which == 1 ? Wk : which == 2 ? Wv : Wp;
    dst = w_bf + w;
  }
  float4 val = ((const float4*)src)[i];
  union { ushort4 u; __hip_bfloat16 h[4]; } c;
  c.h[0] = __float2bfloat16(val.x); c.h[1] = __float2bfloat16(val.y);
  c.h[2] = __float2bfloat16(val.z); c.h[3] = __float2bfloat16(val.w);
  dst[0] = c.u;
}

// -------- vsum[b][c] = sum_{j>=80} v_bf[b,j,c]  (fp32, atomic over 8 rowchunks)
__global__ __launch_bounds__(256) void vsum_kernel(
    const __hip_bfloat16* __restrict__ Vbf, float* __restrict__ vsum)
{
  int b = blockIdx.x >> 3, rc = blockIdx.x & 7;   // 944 = 8 * 118 rows
  int c0 = threadIdx.x * 4;
  int j0 = 80 + rc * 118;
  float s0 = 0.f, s1 = 0.f, s2 = 0.f, s3 = 0.f;
  for (int jj = 0; jj < 118; ++jj) {
    ushort4 u = *(const ushort4*)(Vbf + ((size_t)(b * 1024 + j0 + jj)) * 1024 + c0);
    s0 += b2f(u.x); s1 += b2f(u.y); s2 += b2f(u.z); s3 += b2f(u.w);
  }
  float* dst = vsum + b * 1024 + c0;
  atomicAdd(dst + 0, s0); atomicAdd(dst + 1, s1);
  atomicAdd(dst + 2, s2); atomicAdd(dst + 3, s3);
}

// -------- tails[b][c] = sum_k vsum[b][k] * Wv[c][k]  (4x1024 GEMV) ----------
__global__ __launch_bounds__(256) void tails_kernel(
    const __hip_bfloat16* __restrict__ Wvbf, const float* __restrict__ vsum,
    float* __restrict__ tails)
{
  int b = blockIdx.x >> 2;
  int c = ((blockIdx.x & 3) << 8) + threadIdx.x;
  const float* vs = vsum + b * 1024;
  float acc = 0.f;
  for (int k0 = 0; k0 < 1024; k0 += 8) {
    bf16x8 w = *(const bf16x8*)(Wvbf + (size_t)c * 1024 + k0);
#pragma unroll
    for (int x = 0; x < 8; ++x) acc += vs[k0 + x] * (float)w[x];
  }
  tails[b * 1024 + c] = acc;
}

// ------- bf16 NT GEMM tile: 128x128, K=1024, BK=64 (two 32-col halves) ----
__device__ __forceinline__ void gemm_tile128(
    const __hip_bfloat16* __restrict__ A, const __hip_bfloat16* __restrict__ Bw,
    __hip_bfloat16* __restrict__ C)
{
  const int N = 1024, K = 1024;
  __shared__ __align__(16) __hip_bfloat16 As[2][128 * 32];
  __shared__ __align__(16) __hip_bfloat16 Bs[2][128 * 32];
  const int t = threadIdx.x;
  const int wv = t >> 6, lane = t & 63;
  const int wRow = (wv >> 1) * 64, wCol = (wv & 1) * 64;
  const int mrow = lane & 15, kq = lane >> 4;

  f32x4 acc[4][4] = {};

  for (int k0 = 0; k0 < K; k0 += 64) {
    __syncthreads();
#pragma unroll
    for (int half = 0; half < 2; ++half)
#pragma unroll
      for (int tI = 0; tI < 2; ++tI) {
        int chunk = wv * 2 + tI;              // 0..7, 1024B each within half
        int byteOff = chunk * 1024 + lane * 16;
        int row = byteOff >> 6;
        int colEl = (byteOff & 63) >> 1;
        const __hip_bfloat16* ga = A + (size_t)row * K + k0 + half * 32 + colEl;
        __builtin_amdgcn_global_load_lds(AS1((void*)ga), AS3(&As[half][chunk * 512]), 16, 0, 0);
        const __hip_bfloat16* gb = Bw + (size_t)row * K + k0 + half * 32 + colEl;
        __builtin_amdgcn_global_load_lds(AS1((void*)gb), AS3(&Bs[half][chunk * 512]), 16, 0, 0);
      }
    __syncthreads();

#pragma unroll
    for (int half = 0; half < 2; ++half) {
      bf16x8 af[4], bf[4];
#pragma unroll
      for (int mi = 0; mi < 4; ++mi)
        af[mi] = *(const bf16x8*)&As[half][(wRow + mi * 16 + mrow) * 32 + kq * 8];
#pragma unroll
      for (int ni = 0; ni < 4; ++ni)
        bf[ni] = *(const bf16x8*)&Bs[half][(wCol + ni * 16 + mrow) * 32 + kq * 8];
#pragma unroll
      for (int mi = 0; mi < 4; ++mi)
#pragma unroll
        for (int ni = 0; ni < 4; ++ni)
          acc[mi][ni] = __builtin_amdgcn_mfma_f32_16x16x32_bf16(af[mi], bf[ni], acc[mi][ni], 0, 0, 0);
    }
  }

  // C/D layout: col = lane&15, row = (lane>>4)*4 + r   [m89-verified]
#pragma unroll
  for (int mi = 0; mi < 4; ++mi)
#pragma unroll
    for (int ni = 0; ni < 4; ++ni)
#pragma unroll
      for (int r = 0; r < 4; ++r) {
        int row = wRow + mi * 16 + kq * 4 + r;
        int col = wCol + ni * 16 + mrow;
        C[(size_t)row * N + col] = __float2bfloat16(acc[mi][ni][r]);
      }
}

// QKV: 544 blocks = 8n x (32m_q + 32m_k + 4b_v); q,k full, v only rows [b*1024, b*1024+128)
__global__ __launch_bounds__(256) void qkv_gemm_kernel(
    const __hip_bfloat16* __restrict__ QKVbf, const __hip_bfloat16* __restrict__ Wbf,
    __hip_bfloat16* __restrict__ QKVp)
{
  int l = blockIdx.x;            // 0..543
  int n = l / 68, r = l % 68;
  int z, m;
  if (r < 32)      { z = 0; m = r; }
  else if (r < 64) { z = 1; m = r - 32; }
  else             { z = 2; m = (r - 64) * 8; }   // b -> 128-row tile at row b*1024
  gemm_tile128(
      QKVbf + (size_t)z * 4194304 + (size_t)m * 131072,
      Wbf + (size_t)z * 1048576 + (size_t)n * 131072,
      QKVp + (size_t)z * 4194304 + (size_t)m * 131072 + n * 128);
}

// ------- final GEMM: 128x64 tiles, 512 blocks (2/CU), BK=64 ---------------
__global__ __launch_bounds__(256) void final_gemm_kernel(
    const __hip_bfloat16* __restrict__ Abf, const __hip_bfloat16* __restrict__ Wpbf,
    float* __restrict__ Out, const float* __restrict__ biasAll)
{
  const int N = 1024, K = 1024;
  int l = blockIdx.x;            // 0..511
  int m = l & 31, n = l >> 5;    // m fastest -> A-sharers stride 32 == 0 mod 8 (same XCD)
  const __hip_bfloat16* A = Abf + (size_t)m * 131072;     // 128 rows
  const __hip_bfloat16* Bw = Wpbf + (size_t)n * 65536;    // 64 rows
  float* C = Out + (size_t)m * 131072 + n * 64;
  const float* bias = biasAll + n * 64;

  __shared__ __align__(16) __hip_bfloat16 As[2][128 * 32];
  __shared__ __align__(16) __hip_bfloat16 Bs[2][64 * 32];
  const int t = threadIdx.x;
  const int wv = t >> 6, lane = t & 63;
  const int wRow = (wv >> 1) * 64, wCol = (wv & 1) * 32;
  const int mrow = lane & 15, kq = lane >> 4;

  f32x4 acc[4][2] = {};

  for (int k0 = 0; k0 < K; k0 += 64) {
    __syncthreads();
    // 24 chunks of 1024B per K-step: 16 A (2 halves x 8), 8 B (2 halves x 4)
#pragma unroll
    for (int tI = 0; tI < 6; ++tI) {
      int c = wv * 6 + tI;
      const __hip_bfloat16* gsrc;
      __hip_bfloat16* ldst;
      if (c < 16) {
        int half = c >> 3, ch = c & 7;
        int byteOff = ch * 1024 + lane * 16;
        gsrc = A + (size_t)(byteOff >> 6) * K + k0 + half * 32 + ((byteOff & 63) >> 1);
        ldst = &As[half][ch * 512];
      } else {
        int cb = c - 16; int half = cb >> 2, ch = cb & 3;
        int byteOff = ch * 1024 + lane * 16;
        gsrc = Bw + (size_t)(byteOff >> 6) * K + k0 + half * 32 + ((byteOff & 63) >> 1);
        ldst = &Bs[half][ch * 512];
      }
      __builtin_amdgcn_global_load_lds(AS1((void*)gsrc), AS3(ldst), 16, 0, 0);
    }
    __syncthreads();

#pragma unroll
    for (int half = 0; half < 2; ++half) {
      bf16x8 af[4], bf[2];
#pragma unroll
      for (int mi = 0; mi < 4; ++mi)
        af[mi] = *(const bf16x8*)&As[half][(wRow + mi * 16 + mrow) * 32 + kq * 8];
#pragma unroll
      for (int ni = 0; ni < 2; ++ni)
        bf[ni] = *(const bf16x8*)&Bs[half][(wCol + ni * 16 + mrow) * 32 + kq * 8];
#pragma unroll
      for (int mi = 0; mi < 4; ++mi)
#pragma unroll
        for (int ni = 0; ni < 2; ++ni)
          acc[mi][ni] = __builtin_amdgcn_mfma_f32_16x16x32_bf16(af[mi], bf[ni], acc[mi][ni], 0, 0, 0);
    }
  }

#pragma unroll
  for (int mi = 0; mi < 4; ++mi)
#pragma unroll
    for (int ni = 0; ni < 2; ++ni)
#pragma unroll
      for (int r = 0; r < 4; ++r) {
        int row = wRow + mi * 16 + kq * 4 + r;
        int col = wCol + ni * 16 + mrow;
        // out is never re-read on device: bypass L2 with non-temporal store
        __builtin_nontemporal_store(acc[mi][ni][r] + bias[col],
                                    &C[(size_t)row * N + col]);
      }
}

// ---------------- attention: per (b,h, 64-row i-tile) ---------------------
// LDS: bufA holds csl (f32 64x68) during phases A/B, then vpt (bf16 64x104)
// for phase D. wlb + scalars separate. ~30.4 KB total -> 4 blocks/CU.
__global__ __launch_bounds__(256) void attn_kernel(
    const __hip_bfloat16* __restrict__ QP, const __hip_bfloat16* __restrict__ KP,
    const __hip_bfloat16* __restrict__ VP, const float* __restrict__ tails,
    __hip_bfloat16* __restrict__ OUTA)
{
  const int b = blockIdx.z, h = blockIdx.y, i0 = blockIdx.x * 64;
  const int t = threadIdx.x, lane = t & 63, wv = t >> 6;

  __shared__ __align__(16) char bufA[64 * 68 * 4];      // csl f32 / vpt bf16 overlay
  float (*csl)[68] = (float(*)[68])bufA;                // inclusive cumsum
  __hip_bfloat16 (*vpt)[104] = (__hip_bfloat16(*)[104])bufA;  // vp^T B-operand
  __shared__ __align__(16) __hip_bfloat16 wlb[64][96];  // exp(wei-m), A-operand [i][j]
  __shared__ float scl[64], tlw[64], tail[64];

  if (t < 64) tail[t] = tails[(size_t)b * 1024 + h * 64 + t];

  // phase A: p = qp*kp/8, inclusive cumsum over d.
  {
    const int i = t >> 2, seg = t & 3;
    const size_t base = ((size_t)(b * 1024 + i0 + i)) * 1024 + h * 64 + seg * 16;
    bf16x8 q0 = *(const bf16x8*)(QP + base);
    bf16x8 q1 = *(const bf16x8*)(QP + base + 8);
    bf16x8 k0 = *(const bf16x8*)(KP + base);
    bf16x8 k1 = *(const bf16x8*)(KP + base + 8);
    float cs[16];
    float run = 0.0f;
#pragma unroll
    for (int x = 0; x < 8; ++x) {
      run += (float)q0[x] * (float)k0[x] * 0.125f;
      cs[x] = run;
    }
#pragma unroll
    for (int x = 0; x < 8; ++x) {
      run += (float)q1[x] * (float)k1[x] * 0.125f;
      cs[8 + x] = run;
    }
    float t1 = __shfl_up(run, 1, 4);
    float t2 = __shfl_up(run, 2, 4);
    float t3 = __shfl_up(run, 3, 4);
    float off = 0.0f;
    if (seg > 0) off += t1;
    if (seg > 1) off += t2;
    if (seg > 2) off += t3;
    float4* dst = (float4*)&csl[i][seg * 16];
#pragma unroll
    for (int x4 = 0; x4 < 4; ++x4)
      dst[x4] = make_float4(cs[4 * x4] + off, cs[4 * x4 + 1] + off,
                            cs[4 * x4 + 2] + off, cs[4 * x4 + 3] + off);
  }
  __syncthreads();

  // phase B: wei for j<80, softmax max/sum (tail logit = 0, count 944)
  {
    int i = t >> 2, jg = t & 3;
    float wloc[20];
    float mx = 0.0f;  // includes tail's wei=0
#pragma unroll
    for (int q = 0; q < 20; ++q) {
      int j = jg + 4 * q;
      int s = j - 16; s = s < 0 ? 0 : s;
      int e = j + 16; e = e > 64 ? 64 : e;
      float w = csl[i][e - 1] - (s > 0 ? csl[i][s - 1] : 0.0f);
      wloc[q] = w;
      mx = fmaxf(mx, w);
    }
    mx = fmaxf(mx, __shfl_xor(mx, 1, 64));
    mx = fmaxf(mx, __shfl_xor(mx, 2, 64));
    float sum = 0.0f;
#pragma unroll
    for (int q = 0; q < 20; ++q) {
      float e_ = __expf(wloc[q] - mx);
      wlb[i][jg + 4 * q] = __float2bfloat16(e_);
      sum += e_;
    }
#pragma unroll
    for (int q = 0; q < 4; ++q)      // zero pad j = 80..95
      wlb[i][80 + jg + 4 * q] = __float2bfloat16(0.0f);
    sum += __shfl_xor(sum, 1, 64);
    sum += __shfl_xor(sum, 2, 64);
    float tw = __expf(-mx);
    sum += 944.0f * tw;
    if (jg == 0) { scl[i] = 1.0f / sum; tlw[i] = tw / sum; }
  }
  __syncthreads();   // all csl reads done -> safe to overlay with vpt

  // phase C: stage vp^T[d][j] for j<80; zero-pad j=80..95
  for (int idx = t; idx < 80 * 64; idx += 256) {
    int j = idx >> 6, d = idx & 63;
    vpt[d][j] = VP[((size_t)(b * 1024 + j)) * 1024 + h * 64 + d];
  }
  for (int idx = t; idx < 64 * 16; idx += 256) {
    int d = idx >> 4, j = 80 + (idx & 15);
    vpt[d][j] = __float2bfloat16(0.0f);
  }
  __syncthreads();

  // phase D: O[i][d] = sum_j wl[i][j] * vpt[d][j] via MFMA (M=64,N=64,K=96)
  {
    const int mh = (wv >> 1) * 32, nh = (wv & 1) * 32;
    const int mrow = lane & 15, kq = lane >> 4;
    f32x4 acc[2][2] = {};
#pragma unroll
    for (int k0 = 0; k0 < 96; k0 += 32) {
      bf16x8 af[2], bf[2];
#pragma unroll
      for (int mi = 0; mi < 2; ++mi)
        af[mi] = *(const bf16x8*)&wlb[mh + mi * 16 + mrow][k0 + kq * 8];
#pragma unroll
      for (int ni = 0; ni < 2; ++ni)
        bf[ni] = *(const bf16x8*)&vpt[nh + ni * 16 + mrow][k0 + kq * 8];
#pragma unroll
      for (int mi = 0; mi < 2; ++mi)
#pragma unroll
        for (int ni = 0; ni < 2; ++ni)
          acc[mi][ni] = __builtin_amdgcn_mfma_f32_16x16x32_bf16(af[mi], bf[ni], acc[mi][ni], 0, 0, 0);
    }
#pragma unroll
    for (int mi = 0; mi < 2; ++mi)
#pragma unroll
      for (int ni = 0; ni < 2; ++ni)
#pragma unroll
        for (int r = 0; r < 4; ++r) {
          int i = mh + mi * 16 + kq * 4 + r;
          int d = nh + ni * 16 + mrow;
          float o = acc[mi][ni][r] * scl[i] + tlw[i] * tail[d];
          OUTA[((size_t)(b * 1024 + i0 + i)) * 1024 + h * 64 + d] = __float2bfloat16(o);
        }
  }
}

// ---------------- launch ---------------------------------------------------
extern "C" void kernel_launch(void* const* d_in, const int* in_sizes, int n_in,
                              void* d_out, int out_size, void* d_ws, size_t ws_size,
                              hipStream_t stream)
{
  (void)in_sizes; (void)n_in; (void)out_size; (void)ws_size;
  const float* q  = (const float*)d_in[0];
  const float* k  = (const float*)d_in[1];
  const float* v  = (const float*)d_in[2];
  const float* Wq = (const float*)d_in[3];
  const float* Wk = (const float*)d_in[4];
  const float* Wv = (const float*)d_in[5];
  const float* Wp = (const float*)d_in[6];
  const float* bp = (const float*)d_in[7];

  char* ws = (char*)d_ws;
  __hip_bfloat16* qkv_bf = (__hip_bfloat16*)(ws);              // 24 MB (q,k,v bf16)
  __hip_bfloat16* w_bf   = (__hip_bfloat16*)(ws + 25165824);   // 8 MB (Wq,Wk,Wv,Wp)
  __hip_bfloat16* QKVp   = (__hip_bfloat16*)(ws + 33554432);   // 24 MB (qp,kp,vp bf16)
  __hip_bfloat16* OUTA   = (__hip_bfloat16*)(ws + 58720256);   // 8 MB
  float*          tails  = (float*)(ws + 67108864);            // 16 KB fp32
  float*          vsum   = (float*)(ws + 67108864 + 16384);    // 16 KB fp32
  float* out = (float*)d_out;

  cvt_kernel<<<dim3(16385), 256, 0, stream>>>(q, k, v, Wq, Wk, Wv, Wp,
      (ushort4*)qkv_bf, (ushort4*)w_bf, vsum);
  vsum_kernel<<<dim3(32), 256, 0, stream>>>(qkv_bf + (size_t)2 * 4194304, vsum);
  tails_kernel<<<dim3(16), 256, 0, stream>>>(w_bf + (size_t)2 * 1048576, vsum, tails);
  qkv_gemm_kernel<<<dim3(544), 256, 0, stream>>>(qkv_bf, w_bf, QKVp);
  attn_kernel<<<dim3(16, 16, 4), 256, 0, stream>>>(QKVp, QKVp + (size_t)4194304,
                                                   QKVp + (size_t)2 * 4194304, tails, OUTA);
  final_gemm_kernel<<<dim3(512), 256, 0, stream>>>(OUTA, w_bf + (size_t)3 * 1048576,
                                                   out, bp);
}

// Round 2
// 219.287 us; speedup vs baseline: 1.0150x; 1.0150x over previous
//
#include <hip/hip_runtime.h>
#include <hip/hip_bf16.h>
#include <stdint.h>

// B=4, T=1024, C=1024, H=16, D=64, ks=16
// wei[b,h,i,j] = cs[i][e(j)] - cs[i][s(j)], s=clip(j-16,0,64), e=clip(j+16,0,64)
// => wei==0 for j>=80; softmax tail folds into one weight * tail-sum of vp.
// R10: fix R9's latency-bound tail path. vsum gets 236 blocks + full unroll
//      (16 indep loads in flight); tails GEMV rides inside qkv launch as 8
//      extra co-resident blocks (hidden under the GEMM). 5 launches total.

typedef __bf16 bf16x8 __attribute__((ext_vector_type(8)));
typedef float f32x4 __attribute__((ext_vector_type(4)));

#define AS1(p) ((__attribute__((address_space(1))) void*)(p))
#define AS3(p) ((__attribute__((address_space(3))) void*)(p))

__device__ __forceinline__ float b2f(unsigned short h) {
  union { unsigned int u; float f; } x; x.u = ((unsigned int)h) << 16; return x.f;
}

// ---------------- fused fp32 -> bf16 convert (float4 per thread) ----------
// flat: idx<3M -> q,k,v (1M float4 each); else -> Wq,Wk,Wv,Wp (256K each).
// Block 16384 zeroes the 4096-float vsum buffer (consumer vsum_kernel is a
// later launch on the same stream).
__global__ __launch_bounds__(256) void cvt_kernel(
    const float* __restrict__ q, const float* __restrict__ k,
    const float* __restrict__ v, const float* __restrict__ Wq,
    const float* __restrict__ Wk, const float* __restrict__ Wv,
    const float* __restrict__ Wp,
    ushort4* __restrict__ qkv_bf, ushort4* __restrict__ w_bf,
    float* __restrict__ vsum)
{
  if (blockIdx.x == 16384) {
    float4* tz = (float4*)vsum;
    tz[threadIdx.x * 4 + 0] = make_float4(0.f, 0.f, 0.f, 0.f);
    tz[threadIdx.x * 4 + 1] = make_float4(0.f, 0.f, 0.f, 0.f);
    tz[threadIdx.x * 4 + 2] = make_float4(0.f, 0.f, 0.f, 0.f);
    tz[threadIdx.x * 4 + 3] = make_float4(0.f, 0.f, 0.f, 0.f);
    return;
  }
  int idx = blockIdx.x * 256 + threadIdx.x;
  const float* src; ushort4* dst; int i;
  if (idx < 3145728) {
    int which = idx >> 20; i = idx & 1048575;
    src = which == 0 ? q : which == 1 ? k : v;
    dst = qkv_bf + (size_t)which * 1048576 + i;
  } else {
    int w = idx - 3145728; int which = w >> 18; i = w & 262143;
    src = which == 0 ? Wq : which == 1 ? Wk : which == 2 ? Wv : Wp;
    dst = w_bf + w;
  }
  float4 val = ((const float4*)src)[i];
  union { ushort4 u; __hip_bfloat16 h[4]; } c;
  c.h[0] = __float2bfloat16(val.x); c.h[1] = __float2bfloat16(val.y);
  c.h[2] = __float2bfloat16(val.z); c.h[3] = __float2bfloat16(val.w);
  dst[0] = c.u;
}

// -------- vsum[b][c] = sum_{j>=80} v_bf[b,j,c]  (fp32 atomics) -------------
// 944 tail rows = 59 chunks x 16 rows; grid 236 = 4b x 59. Full unroll gives
// 16 independent ushort4 loads in flight per thread (R9's 118-iter serial
// loop was ~30us latency-bound).
__global__ __launch_bounds__(256) void vsum_kernel(
    const __hip_bfloat16* __restrict__ Vbf, float* __restrict__ vsum)
{
  int b = blockIdx.x / 59, rc = blockIdx.x % 59;
  int c0 = threadIdx.x * 4;
  int j0 = 80 + rc * 16;
  const __hip_bfloat16* base = Vbf + ((size_t)(b * 1024 + j0)) * 1024 + c0;
  float s0 = 0.f, s1 = 0.f, s2 = 0.f, s3 = 0.f;
#pragma unroll
  for (int jj = 0; jj < 16; ++jj) {
    ushort4 u = *(const ushort4*)(base + (size_t)jj * 1024);
    s0 += b2f(u.x); s1 += b2f(u.y); s2 += b2f(u.z); s3 += b2f(u.w);
  }
  float* dst = vsum + b * 1024 + c0;
  atomicAdd(dst + 0, s0); atomicAdd(dst + 1, s1);
  atomicAdd(dst + 2, s2); atomicAdd(dst + 3, s3);
}

// ------- bf16 NT GEMM tile: 128x128, K=1024, BK=64 (two 32-col halves) ----
__device__ __forceinline__ void gemm_tile128(
    const __hip_bfloat16* __restrict__ A, const __hip_bfloat16* __restrict__ Bw,
    __hip_bfloat16* __restrict__ C)
{
  const int N = 1024, K = 1024;
  __shared__ __align__(16) __hip_bfloat16 As[2][128 * 32];
  __shared__ __align__(16) __hip_bfloat16 Bs[2][128 * 32];
  const int t = threadIdx.x;
  const int wv = t >> 6, lane = t & 63;
  const int wRow = (wv >> 1) * 64, wCol = (wv & 1) * 64;
  const int mrow = lane & 15, kq = lane >> 4;

  f32x4 acc[4][4] = {};

  for (int k0 = 0; k0 < K; k0 += 64) {
    __syncthreads();
#pragma unroll
    for (int half = 0; half < 2; ++half)
#pragma unroll
      for (int tI = 0; tI < 2; ++tI) {
        int chunk = wv * 2 + tI;              // 0..7, 1024B each within half
        int byteOff = chunk * 1024 + lane * 16;
        int row = byteOff >> 6;
        int colEl = (byteOff & 63) >> 1;
        const __hip_bfloat16* ga = A + (size_t)row * K + k0 + half * 32 + colEl;
        __builtin_amdgcn_global_load_lds(AS1((void*)ga), AS3(&As[half][chunk * 512]), 16, 0, 0);
        const __hip_bfloat16* gb = Bw + (size_t)row * K + k0 + half * 32 + colEl;
        __builtin_amdgcn_global_load_lds(AS1((void*)gb), AS3(&Bs[half][chunk * 512]), 16, 0, 0);
      }
    __syncthreads();

#pragma unroll
    for (int half = 0; half < 2; ++half) {
      bf16x8 af[4], bf[4];
#pragma unroll
      for (int mi = 0; mi < 4; ++mi)
        af[mi] = *(const bf16x8*)&As[half][(wRow + mi * 16 + mrow) * 32 + kq * 8];
#pragma unroll
      for (int ni = 0; ni < 4; ++ni)
        bf[ni] = *(const bf16x8*)&Bs[half][(wCol + ni * 16 + mrow) * 32 + kq * 8];
#pragma unroll
      for (int mi = 0; mi < 4; ++mi)
#pragma unroll
        for (int ni = 0; ni < 4; ++ni)
          acc[mi][ni] = __builtin_amdgcn_mfma_f32_16x16x32_bf16(af[mi], bf[ni], acc[mi][ni], 0, 0, 0);
    }
  }

  // C/D layout: col = lane&15, row = (lane>>4)*4 + r   [m89-verified]
#pragma unroll
  for (int mi = 0; mi < 4; ++mi)
#pragma unroll
    for (int ni = 0; ni < 4; ++ni)
#pragma unroll
      for (int r = 0; r < 4; ++r) {
        int row = wRow + mi * 16 + kq * 4 + r;
        int col = wCol + ni * 16 + mrow;
        C[(size_t)row * N + col] = __float2bfloat16(acc[mi][ni][r]);
      }
}

// QKV: 552 blocks. [0,544): 8n x (32m_q + 32m_k + 4b_v) GEMM tiles.
// [544,552): tails[b][c] = sum_k vsum[b][k]*Wv[c][k] GEMV, co-resident with
// the GEMM blocks (hidden under them); reads vsum from the prior launch.
__global__ __launch_bounds__(256) void qkv_gemm_kernel(
    const __hip_bfloat16* __restrict__ QKVbf, const __hip_bfloat16* __restrict__ Wbf,
    __hip_bfloat16* __restrict__ QKVp, const float* __restrict__ vsum,
    float* __restrict__ tails)
{
  int l = blockIdx.x;            // 0..551
  if (l >= 544) {                // tails GEMV: 2048 threads, 2 outputs each
    int o = (l - 544) * 512 + (int)threadIdx.x * 2;   // (b,c) pairs, c even
    int b = o >> 10, c = o & 1023;
    const float* vs = vsum + b * 1024;
    const __hip_bfloat16* w0 = Wbf + (size_t)2 * 1048576 + (size_t)c * 1024;
    const __hip_bfloat16* w1 = w0 + 1024;
    float a0 = 0.f, a1 = 0.f;
#pragma unroll 4
    for (int k0 = 0; k0 < 1024; k0 += 8) {
      bf16x8 wA = *(const bf16x8*)(w0 + k0);
      bf16x8 wB = *(const bf16x8*)(w1 + k0);
#pragma unroll
      for (int x = 0; x < 8; ++x) {
        float vv = vs[k0 + x];
        a0 += vv * (float)wA[x];
        a1 += vv * (float)wB[x];
      }
    }
    tails[b * 1024 + c] = a0;
    tails[b * 1024 + c + 1] = a1;
    return;
  }
  int n = l / 68, r = l % 68;
  int z, m;
  if (r < 32)      { z = 0; m = r; }
  else if (r < 64) { z = 1; m = r - 32; }
  else             { z = 2; m = (r - 64) * 8; }   // b -> 128-row tile at row b*1024
  gemm_tile128(
      QKVbf + (size_t)z * 4194304 + (size_t)m * 131072,
      Wbf + (size_t)z * 1048576 + (size_t)n * 131072,
      QKVp + (size_t)z * 4194304 + (size_t)m * 131072 + n * 128);
}

// ------- final GEMM: 128x64 tiles, 512 blocks (2/CU), BK=64 ---------------
__global__ __launch_bounds__(256) void final_gemm_kernel(
    const __hip_bfloat16* __restrict__ Abf, const __hip_bfloat16* __restrict__ Wpbf,
    float* __restrict__ Out, const float* __restrict__ biasAll)
{
  const int N = 1024, K = 1024;
  int l = blockIdx.x;            // 0..511
  int m = l & 31, n = l >> 5;    // m fastest -> A-sharers stride 32 == 0 mod 8 (same XCD)
  const __hip_bfloat16* A = Abf + (size_t)m * 131072;     // 128 rows
  const __hip_bfloat16* Bw = Wpbf + (size_t)n * 65536;    // 64 rows
  float* C = Out + (size_t)m * 131072 + n * 64;
  const float* bias = biasAll + n * 64;

  __shared__ __align__(16) __hip_bfloat16 As[2][128 * 32];
  __shared__ __align__(16) __hip_bfloat16 Bs[2][64 * 32];
  const int t = threadIdx.x;
  const int wv = t >> 6, lane = t & 63;
  const int wRow = (wv >> 1) * 64, wCol = (wv & 1) * 32;
  const int mrow = lane & 15, kq = lane >> 4;

  f32x4 acc[4][2] = {};

  for (int k0 = 0; k0 < K; k0 += 64) {
    __syncthreads();
    // 24 chunks of 1024B per K-step: 16 A (2 halves x 8), 8 B (2 halves x 4)
#pragma unroll
    for (int tI = 0; tI < 6; ++tI) {
      int c = wv * 6 + tI;
      const __hip_bfloat16* gsrc;
      __hip_bfloat16* ldst;
      if (c < 16) {
        int half = c >> 3, ch = c & 7;
        int byteOff = ch * 1024 + lane * 16;
        gsrc = A + (size_t)(byteOff >> 6) * K + k0 + half * 32 + ((byteOff & 63) >> 1);
        ldst = &As[half][ch * 512];
      } else {
        int cb = c - 16; int half = cb >> 2, ch = cb & 3;
        int byteOff = ch * 1024 + lane * 16;
        gsrc = Bw + (size_t)(byteOff >> 6) * K + k0 + half * 32 + ((byteOff & 63) >> 1);
        ldst = &Bs[half][ch * 512];
      }
      __builtin_amdgcn_global_load_lds(AS1((void*)gsrc), AS3(ldst), 16, 0, 0);
    }
    __syncthreads();

#pragma unroll
    for (int half = 0; half < 2; ++half) {
      bf16x8 af[4], bf[2];
#pragma unroll
      for (int mi = 0; mi < 4; ++mi)
        af[mi] = *(const bf16x8*)&As[half][(wRow + mi * 16 + mrow) * 32 + kq * 8];
#pragma unroll
      for (int ni = 0; ni < 2; ++ni)
        bf[ni] = *(const bf16x8*)&Bs[half][(wCol + ni * 16 + mrow) * 32 + kq * 8];
#pragma unroll
      for (int mi = 0; mi < 4; ++mi)
#pragma unroll
        for (int ni = 0; ni < 2; ++ni)
          acc[mi][ni] = __builtin_amdgcn_mfma_f32_16x16x32_bf16(af[mi], bf[ni], acc[mi][ni], 0, 0, 0);
    }
  }

#pragma unroll
  for (int mi = 0; mi < 4; ++mi)
#pragma unroll
    for (int ni = 0; ni < 2; ++ni)
#pragma unroll
      for (int r = 0; r < 4; ++r) {
        int row = wRow + mi * 16 + kq * 4 + r;
        int col = wCol + ni * 16 + mrow;
        // out is never re-read on device: bypass L2 with non-temporal store
        __builtin_nontemporal_store(acc[mi][ni][r] + bias[col],
                                    &C[(size_t)row * N + col]);
      }
}

// ---------------- attention: per (b,h, 64-row i-tile) ---------------------
// LDS: bufA holds csl (f32 64x68) during phases A/B, then vpt (bf16 64x104)
// for phase D. wlb + scalars separate. ~30.4 KB total -> 4 blocks/CU.
__global__ __launch_bounds__(256) void attn_kernel(
    const __hip_bfloat16* __restrict__ QP, const __hip_bfloat16* __restrict__ KP,
    const __hip_bfloat16* __restrict__ VP, const float* __restrict__ tails,
    __hip_bfloat16* __restrict__ OUTA)
{
  const int b = blockIdx.z, h = blockIdx.y, i0 = blockIdx.x * 64;
  const int t = threadIdx.x, lane = t & 63, wv = t >> 6;

  __shared__ __align__(16) char bufA[64 * 68 * 4];      // csl f32 / vpt bf16 overlay
  float (*csl)[68] = (float(*)[68])bufA;                // inclusive cumsum
  __hip_bfloat16 (*vpt)[104] = (__hip_bfloat16(*)[104])bufA;  // vp^T B-operand
  __shared__ __align__(16) __hip_bfloat16 wlb[64][96];  // exp(wei-m), A-operand [i][j]
  __shared__ float scl[64], tlw[64], tail[64];

  if (t < 64) tail[t] = tails[(size_t)b * 1024 + h * 64 + t];

  // phase A: p = qp*kp/8, inclusive cumsum over d.
  {
    const int i = t >> 2, seg = t & 3;
    const size_t base = ((size_t)(b * 1024 + i0 + i)) * 1024 + h * 64 + seg * 16;
    bf16x8 q0 = *(const bf16x8*)(QP + base);
    bf16x8 q1 = *(const bf16x8*)(QP + base + 8);
    bf16x8 k0 = *(const bf16x8*)(KP + base);
    bf16x8 k1 = *(const bf16x8*)(KP + base + 8);
    float cs[16];
    float run = 0.0f;
#pragma unroll
    for (int x = 0; x < 8; ++x) {
      run += (float)q0[x] * (float)k0[x] * 0.125f;
      cs[x] = run;
    }
#pragma unroll
    for (int x = 0; x < 8; ++x) {
      run += (float)q1[x] * (float)k1[x] * 0.125f;
      cs[8 + x] = run;
    }
    float t1 = __shfl_up(run, 1, 4);
    float t2 = __shfl_up(run, 2, 4);
    float t3 = __shfl_up(run, 3, 4);
    float off = 0.0f;
    if (seg > 0) off += t1;
    if (seg > 1) off += t2;
    if (seg > 2) off += t3;
    float4* dst = (float4*)&csl[i][seg * 16];
#pragma unroll
    for (int x4 = 0; x4 < 4; ++x4)
      dst[x4] = make_float4(cs[4 * x4] + off, cs[4 * x4 + 1] + off,
                            cs[4 * x4 + 2] + off, cs[4 * x4 + 3] + off);
  }
  __syncthreads();

  // phase B: wei for j<80, softmax max/sum (tail logit = 0, count 944)
  {
    int i = t >> 2, jg = t & 3;
    float wloc[20];
    float mx = 0.0f;  // includes tail's wei=0
#pragma unroll
    for (int q = 0; q < 20; ++q) {
      int j = jg + 4 * q;
      int s = j - 16; s = s < 0 ? 0 : s;
      int e = j + 16; e = e > 64 ? 64 : e;
      float w = csl[i][e - 1] - (s > 0 ? csl[i][s - 1] : 0.0f);
      wloc[q] = w;
      mx = fmaxf(mx, w);
    }
    mx = fmaxf(mx, __shfl_xor(mx, 1, 64));
    mx = fmaxf(mx, __shfl_xor(mx, 2, 64));
    float sum = 0.0f;
#pragma unroll
    for (int q = 0; q < 20; ++q) {
      float e_ = __expf(wloc[q] - mx);
      wlb[i][jg + 4 * q] = __float2bfloat16(e_);
      sum += e_;
    }
#pragma unroll
    for (int q = 0; q < 4; ++q)      // zero pad j = 80..95
      wlb[i][80 + jg + 4 * q] = __float2bfloat16(0.0f);
    sum += __shfl_xor(sum, 1, 64);
    sum += __shfl_xor(sum, 2, 64);
    float tw = __expf(-mx);
    sum += 944.0f * tw;
    if (jg == 0) { scl[i] = 1.0f / sum; tlw[i] = tw / sum; }
  }
  __syncthreads();   // all csl reads done -> safe to overlay with vpt

  // phase C: stage vp^T[d][j] for j<80; zero-pad j=80..95
  for (int idx = t; idx < 80 * 64; idx += 256) {
    int j = idx >> 6, d = idx & 63;
    vpt[d][j] = VP[((size_t)(b * 1024 + j)) * 1024 + h * 64 + d];
  }
  for (int idx = t; idx < 64 * 16; idx += 256) {
    int d = idx >> 4, j = 80 + (idx & 15);
    vpt[d][j] = __float2bfloat16(0.0f);
  }
  __syncthreads();

  // phase D: O[i][d] = sum_j wl[i][j] * vpt[d][j] via MFMA (M=64,N=64,K=96)
  {
    const int mh = (wv >> 1) * 32, nh = (wv & 1) * 32;
    const int mrow = lane & 15, kq = lane >> 4;
    f32x4 acc[2][2] = {};
#pragma unroll
    for (int k0 = 0; k0 < 96; k0 += 32) {
      bf16x8 af[2], bf[2];
#pragma unroll
      for (int mi = 0; mi < 2; ++mi)
        af[mi] = *(const bf16x8*)&wlb[mh + mi * 16 + mrow][k0 + kq * 8];
#pragma unroll
      for (int ni = 0; ni < 2; ++ni)
        bf[ni] = *(const bf16x8*)&vpt[nh + ni * 16 + mrow][k0 + kq * 8];
#pragma unroll
      for (int mi = 0; mi < 2; ++mi)
#pragma unroll
        for (int ni = 0; ni < 2; ++ni)
          acc[mi][ni] = __builtin_amdgcn_mfma_f32_16x16x32_bf16(af[mi], bf[ni], acc[mi][ni], 0, 0, 0);
    }
#pragma unroll
    for (int mi = 0; mi < 2; ++mi)
#pragma unroll
      for (int ni = 0; ni < 2; ++ni)
#pragma unroll
        for (int r = 0; r < 4; ++r) {
          int i = mh + mi * 16 + kq * 4 + r;
          int d = nh + ni * 16 + mrow;
          float o = acc[mi][ni][r] * scl[i] + tlw[i] * tail[d];
          OUTA[((size_t)(b * 1024 + i0 + i)) * 1024 + h * 64 + d] = __float2bfloat16(o);
        }
  }
}

// ---------------- launch ---------------------------------------------------
extern "C" void kernel_launch(void* const* d_in, const int* in_sizes, int n_in,
                              void* d_out, int out_size, void* d_ws, size_t ws_size,
                              hipStream_t stream)
{
  (void)in_sizes; (void)n_in; (void)out_size; (void)ws_size;
  const float* q  = (const float*)d_in[0];
  const float* k  = (const float*)d_in[1];
  const float* v  = (const float*)d_in[2];
  const float* Wq = (const float*)d_in[3];
  const float* Wk = (const float*)d_in[4];
  const float* Wv = (const float*)d_in[5];
  const float* Wp = (const float*)d_in[6];
  const float* bp = (const float*)d_in[7];

  char* ws = (char*)d_ws;
  __hip_bfloat16* qkv_bf = (__hip_bfloat16*)(ws);              // 24 MB (q,k,v bf16)
  __hip_bfloat16* w_bf   = (__hip_bfloat16*)(ws + 25165824);   // 8 MB (Wq,Wk,Wv,Wp)
  __hip_bfloat16* QKVp   = (__hip_bfloat16*)(ws + 33554432);   // 24 MB (qp,kp,vp bf16)
  __hip_bfloat16* OUTA   = (__hip_bfloat16*)(ws + 58720256);   // 8 MB
  float*          tails  = (float*)(ws + 67108864);            // 16 KB fp32
  float*          vsum   = (float*)(ws + 67108864 + 16384);    // 16 KB fp32
  float* out = (float*)d_out;

  cvt_kernel<<<dim3(16385), 256, 0, stream>>>(q, k, v, Wq, Wk, Wv, Wp,
      (ushort4*)qkv_bf, (ushort4*)w_bf, vsum);
  vsum_kernel<<<dim3(236), 256, 0, stream>>>(qkv_bf + (size_t)2 * 4194304, vsum);
  qkv_gemm_kernel<<<dim3(552), 256, 0, stream>>>(qkv_bf, w_bf, QKVp, vsum, tails);
  attn_kernel<<<dim3(16, 16, 4), 256, 0, stream>>>(QKVp, QKVp + (size_t)4194304,
                                                   QKVp + (size_t)2 * 4194304, tails, OUTA);
  final_gemm_kernel<<<dim3(512), 256, 0, stream>>>(OUTA, w_bf + (size_t)3 * 1048576,
                                                   out, bp);
}

// Round 3
// 214.944 us; speedup vs baseline: 1.0355x; 1.0202x over previous
//
#include <hip/hip_runtime.h>
#include <hip/hip_bf16.h>
#include <stdint.h>

// B=4, T=1024, C=1024, H=16, D=64, ks=16
// wei[b,h,i,j] = cs[i][e(j)] - cs[i][s(j)], s=clip(j-16,0,64), e=clip(j+16,0,64)
// => wei==0 for j>=80; softmax tail folds into one weight * tail-sum of vp.
// R11: qkv grid-shape fix. R10's 552-block 128x128 grid ran 2.16 blocks/CU
//      (71us, MfmaUtil 9.5%); uniform 128x64 tiles give 1096 blocks ~4.3/CU
//      (24KB LDS, 5/CU ceiling). final_gemm reverted to R8's measured 64x64.

typedef __bf16 bf16x8 __attribute__((ext_vector_type(8)));
typedef float f32x4 __attribute__((ext_vector_type(4)));

#define AS1(p) ((__attribute__((address_space(1))) void*)(p))
#define AS3(p) ((__attribute__((address_space(3))) void*)(p))

__device__ __forceinline__ float b2f(unsigned short h) {
  union { unsigned int u; float f; } x; x.u = ((unsigned int)h) << 16; return x.f;
}

// ---------------- fused fp32 -> bf16 convert (float4 per thread) ----------
// flat: idx<3M -> q,k,v (1M float4 each); else -> Wq,Wk,Wv,Wp (256K each).
// Block 16384 zeroes the 4096-float vsum buffer (consumer vsum_kernel is a
// later launch on the same stream).
__global__ __launch_bounds__(256) void cvt_kernel(
    const float* __restrict__ q, const float* __restrict__ k,
    const float* __restrict__ v, const float* __restrict__ Wq,
    const float* __restrict__ Wk, const float* __restrict__ Wv,
    const float* __restrict__ Wp,
    ushort4* __restrict__ qkv_bf, ushort4* __restrict__ w_bf,
    float* __restrict__ vsum)
{
  if (blockIdx.x == 16384) {
    float4* tz = (float4*)vsum;
    tz[threadIdx.x * 4 + 0] = make_float4(0.f, 0.f, 0.f, 0.f);
    tz[threadIdx.x * 4 + 1] = make_float4(0.f, 0.f, 0.f, 0.f);
    tz[threadIdx.x * 4 + 2] = make_float4(0.f, 0.f, 0.f, 0.f);
    tz[threadIdx.x * 4 + 3] = make_float4(0.f, 0.f, 0.f, 0.f);
    return;
  }
  int idx = blockIdx.x * 256 + threadIdx.x;
  const float* src; ushort4* dst; int i;
  if (idx < 3145728) {
    int which = idx >> 20; i = idx & 1048575;
    src = which == 0 ? q : which == 1 ? k : v;
    dst = qkv_bf + (size_t)which * 1048576 + i;
  } else {
    int w = idx - 3145728; int which = w >> 18; i = w & 262143;
    src = which == 0 ? Wq : which == 1 ? Wk : which == 2 ? Wv : Wp;
    dst = w_bf + w;
  }
  float4 val = ((const float4*)src)[i];
  union { ushort4 u; __hip_bfloat16 h[4]; } c;
  c.h[0] = __float2bfloat16(val.x); c.h[1] = __float2bfloat16(val.y);
  c.h[2] = __float2bfloat16(val.z); c.h[3] = __float2bfloat16(val.w);
  dst[0] = c.u;
}

// -------- vsum[b][c] = sum_{j>=80} v_bf[b,j,c]  (fp32 atomics) -------------
// 944 tail rows = 59 chunks x 16 rows; grid 236 = 4b x 59. Full unroll gives
// 16 independent ushort4 loads in flight per thread.
__global__ __launch_bounds__(256) void vsum_kernel(
    const __hip_bfloat16* __restrict__ Vbf, float* __restrict__ vsum)
{
  int b = blockIdx.x / 59, rc = blockIdx.x % 59;
  int c0 = threadIdx.x * 4;
  int j0 = 80 + rc * 16;
  const __hip_bfloat16* base = Vbf + ((size_t)(b * 1024 + j0)) * 1024 + c0;
  float s0 = 0.f, s1 = 0.f, s2 = 0.f, s3 = 0.f;
#pragma unroll
  for (int jj = 0; jj < 16; ++jj) {
    ushort4 u = *(const ushort4*)(base + (size_t)jj * 1024);
    s0 += b2f(u.x); s1 += b2f(u.y); s2 += b2f(u.z); s3 += b2f(u.w);
  }
  float* dst = vsum + b * 1024 + c0;
  atomicAdd(dst + 0, s0); atomicAdd(dst + 1, s1);
  atomicAdd(dst + 2, s2); atomicAdd(dst + 3, s3);
}

// ------- bf16 NT GEMM tile: 128 rows x 64 cols, K=1024, BK=64 -------------
// 24KB LDS -> up to 5 blocks/CU co-resident (the overlap the 128x128 tile
// at 2 blocks/CU couldn't get). bf16 epilogue.
__device__ __forceinline__ void gemm128x64(
    const __hip_bfloat16* __restrict__ A, const __hip_bfloat16* __restrict__ Bw,
    __hip_bfloat16* __restrict__ C)
{
  const int N = 1024, K = 1024;
  __shared__ __align__(16) __hip_bfloat16 As[2][128 * 32];
  __shared__ __align__(16) __hip_bfloat16 Bs[2][64 * 32];
  const int t = threadIdx.x;
  const int wv = t >> 6, lane = t & 63;
  const int wRow = (wv >> 1) * 64, wCol = (wv & 1) * 32;
  const int mrow = lane & 15, kq = lane >> 4;

  f32x4 acc[4][2] = {};

  for (int k0 = 0; k0 < K; k0 += 64) {
    __syncthreads();
    // 24 chunks of 1024B per K-step: 16 A (2 halves x 8), 8 B (2 halves x 4)
#pragma unroll
    for (int tI = 0; tI < 6; ++tI) {
      int c = wv * 6 + tI;
      const __hip_bfloat16* gsrc;
      __hip_bfloat16* ldst;
      if (c < 16) {
        int half = c >> 3, ch = c & 7;
        int byteOff = ch * 1024 + lane * 16;
        gsrc = A + (size_t)(byteOff >> 6) * K + k0 + half * 32 + ((byteOff & 63) >> 1);
        ldst = &As[half][ch * 512];
      } else {
        int cb = c - 16; int half = cb >> 2, ch = cb & 3;
        int byteOff = ch * 1024 + lane * 16;
        gsrc = Bw + (size_t)(byteOff >> 6) * K + k0 + half * 32 + ((byteOff & 63) >> 1);
        ldst = &Bs[half][ch * 512];
      }
      __builtin_amdgcn_global_load_lds(AS1((void*)gsrc), AS3(ldst), 16, 0, 0);
    }
    __syncthreads();

#pragma unroll
    for (int half = 0; half < 2; ++half) {
      bf16x8 af[4], bf[2];
#pragma unroll
      for (int mi = 0; mi < 4; ++mi)
        af[mi] = *(const bf16x8*)&As[half][(wRow + mi * 16 + mrow) * 32 + kq * 8];
#pragma unroll
      for (int ni = 0; ni < 2; ++ni)
        bf[ni] = *(const bf16x8*)&Bs[half][(wCol + ni * 16 + mrow) * 32 + kq * 8];
#pragma unroll
      for (int mi = 0; mi < 4; ++mi)
#pragma unroll
        for (int ni = 0; ni < 2; ++ni)
          acc[mi][ni] = __builtin_amdgcn_mfma_f32_16x16x32_bf16(af[mi], bf[ni], acc[mi][ni], 0, 0, 0);
    }
  }

  // C/D layout: col = lane&15, row = (lane>>4)*4 + r   [m89-verified]
#pragma unroll
  for (int mi = 0; mi < 4; ++mi)
#pragma unroll
    for (int ni = 0; ni < 2; ++ni)
#pragma unroll
      for (int r = 0; r < 4; ++r) {
        int row = wRow + mi * 16 + kq * 4 + r;
        int col = wCol + ni * 16 + mrow;
        C[(size_t)row * N + col] = __float2bfloat16(acc[mi][ni][r]);
      }
}

// QKV: 1096 blocks, ~4.3/CU.
//   [0,1024):   q,k at 128x64: z = l>>9, n = (l&511)>>5 (16), m = l&31 (32)
//   [1024,1088): v at 128x64, only rows [b*1024, b*1024+128): b=(r>>4), n=r&15
//   [1088,1096): tails[b][c] = sum_k vsum[b][k]*Wv[c][k] GEMV (co-resident)
__global__ __launch_bounds__(256) void qkv_gemm_kernel(
    const __hip_bfloat16* __restrict__ QKVbf, const __hip_bfloat16* __restrict__ Wbf,
    __hip_bfloat16* __restrict__ QKVp, const float* __restrict__ vsum,
    float* __restrict__ tails)
{
  int l = blockIdx.x;            // 0..1095
  if (l >= 1088) {               // tails GEMV: 2048 threads, 2 outputs each
    int o = (l - 1088) * 512 + (int)threadIdx.x * 2;  // (b,c) pairs, c even
    int b = o >> 10, c = o & 1023;
    const float* vs = vsum + b * 1024;
    const __hip_bfloat16* w0 = Wbf + (size_t)2 * 1048576 + (size_t)c * 1024;
    const __hip_bfloat16* w1 = w0 + 1024;
    float a0 = 0.f, a1 = 0.f;
#pragma unroll 4
    for (int k0 = 0; k0 < 1024; k0 += 8) {
      bf16x8 wA = *(const bf16x8*)(w0 + k0);
      bf16x8 wB = *(const bf16x8*)(w1 + k0);
#pragma unroll
      for (int x = 0; x < 8; ++x) {
        float vv = vs[k0 + x];
        a0 += vv * (float)wA[x];
        a1 += vv * (float)wB[x];
      }
    }
    tails[b * 1024 + c] = a0;
    tails[b * 1024 + c + 1] = a1;
    return;
  }
  int z, m, n;
  if (l < 1024) { z = l >> 9; int r = l & 511; n = r >> 5; m = r & 31; }
  else          { z = 2; int r = l - 1024; m = (r >> 4) * 8; n = r & 15; }
  gemm128x64(
      QKVbf + (size_t)z * 4194304 + (size_t)m * 131072,
      Wbf + (size_t)z * 1048576 + (size_t)n * 65536,
      QKVp + (size_t)z * 4194304 + (size_t)m * 131072 + n * 64);
}

// ------- final GEMM: 64x64 tiles, 1024 blocks (4/CU), BK=64 ---------------
// (R8's measured configuration.)
__global__ __launch_bounds__(256) void final_gemm_kernel(
    const __hip_bfloat16* __restrict__ Abf, const __hip_bfloat16* __restrict__ Wpbf,
    float* __restrict__ Out, const float* __restrict__ biasAll)
{
  const int N = 1024, K = 1024;
  int l = blockIdx.x;            // 0..1023
  int m = l & 63, n = l >> 6;    // m fastest -> XCD A-strip reuse
  const __hip_bfloat16* A = Abf + (size_t)m * 65536;      // 64 rows
  const __hip_bfloat16* Bw = Wpbf + (size_t)n * 65536;    // 64 rows
  float* C = Out + (size_t)m * 65536 + n * 64;
  const float* bias = biasAll + n * 64;

  __shared__ __align__(16) __hip_bfloat16 As[2][64 * 32];
  __shared__ __align__(16) __hip_bfloat16 Bs[2][64 * 32];
  const int t = threadIdx.x;
  const int wv = t >> 6, lane = t & 63;
  const int wRow = (wv >> 1) * 32, wCol = (wv & 1) * 32;
  const int mrow = lane & 15, kq = lane >> 4;

  f32x4 acc[2][2] = {};

  for (int k0 = 0; k0 < K; k0 += 64) {
    __syncthreads();
#pragma unroll
    for (int tI = 0; tI < 4; ++tI) {
      int c = wv * 4 + tI;                     // 0..15 chunks of 1024B
      int half, ch;
      const __hip_bfloat16* gsrc;
      __hip_bfloat16* ldst;
      if (c < 8) { half = c >> 2; ch = c & 3;
        int byteOff = ch * 1024 + lane * 16;
        gsrc = A + (size_t)(byteOff >> 6) * K + k0 + half * 32 + ((byteOff & 63) >> 1);
        ldst = &As[half][ch * 512];
      } else { int cb = c - 8; half = cb >> 2; ch = cb & 3;
        int byteOff = ch * 1024 + lane * 16;
        gsrc = Bw + (size_t)(byteOff >> 6) * K + k0 + half * 32 + ((byteOff & 63) >> 1);
        ldst = &Bs[half][ch * 512];
      }
      __builtin_amdgcn_global_load_lds(AS1((void*)gsrc), AS3(ldst), 16, 0, 0);
    }
    __syncthreads();

#pragma unroll
    for (int half = 0; half < 2; ++half) {
      bf16x8 af[2], bf[2];
#pragma unroll
      for (int mi = 0; mi < 2; ++mi)
        af[mi] = *(const bf16x8*)&As[half][(wRow + mi * 16 + mrow) * 32 + kq * 8];
#pragma unroll
      for (int ni = 0; ni < 2; ++ni)
        bf[ni] = *(const bf16x8*)&Bs[half][(wCol + ni * 16 + mrow) * 32 + kq * 8];
#pragma unroll
      for (int mi = 0; mi < 2; ++mi)
#pragma unroll
        for (int ni = 0; ni < 2; ++ni)
          acc[mi][ni] = __builtin_amdgcn_mfma_f32_16x16x32_bf16(af[mi], bf[ni], acc[mi][ni], 0, 0, 0);
    }
  }

#pragma unroll
  for (int mi = 0; mi < 2; ++mi)
#pragma unroll
    for (int ni = 0; ni < 2; ++ni)
#pragma unroll
      for (int r = 0; r < 4; ++r) {
        int row = wRow + mi * 16 + kq * 4 + r;
        int col = wCol + ni * 16 + mrow;
        // out is never re-read on device: bypass L2 with non-temporal store
        __builtin_nontemporal_store(acc[mi][ni][r] + bias[col],
                                    &C[(size_t)row * N + col]);
      }
}

// ---------------- attention: per (b,h, 64-row i-tile) ---------------------
// LDS: bufA holds csl (f32 64x68) during phases A/B, then vpt (bf16 64x104)
// for phase D. wlb + scalars separate. ~30.4 KB total -> 4 blocks/CU.
__global__ __launch_bounds__(256) void attn_kernel(
    const __hip_bfloat16* __restrict__ QP, const __hip_bfloat16* __restrict__ KP,
    const __hip_bfloat16* __restrict__ VP, const float* __restrict__ tails,
    __hip_bfloat16* __restrict__ OUTA)
{
  const int b = blockIdx.z, h = blockIdx.y, i0 = blockIdx.x * 64;
  const int t = threadIdx.x, lane = t & 63, wv = t >> 6;

  __shared__ __align__(16) char bufA[64 * 68 * 4];      // csl f32 / vpt bf16 overlay
  float (*csl)[68] = (float(*)[68])bufA;                // inclusive cumsum
  __hip_bfloat16 (*vpt)[104] = (__hip_bfloat16(*)[104])bufA;  // vp^T B-operand
  __shared__ __align__(16) __hip_bfloat16 wlb[64][96];  // exp(wei-m), A-operand [i][j]
  __shared__ float scl[64], tlw[64], tail[64];

  if (t < 64) tail[t] = tails[(size_t)b * 1024 + h * 64 + t];

  // phase A: p = qp*kp/8, inclusive cumsum over d.
  {
    const int i = t >> 2, seg = t & 3;
    const size_t base = ((size_t)(b * 1024 + i0 + i)) * 1024 + h * 64 + seg * 16;
    bf16x8 q0 = *(const bf16x8*)(QP + base);
    bf16x8 q1 = *(const bf16x8*)(QP + base + 8);
    bf16x8 k0 = *(const bf16x8*)(KP + base);
    bf16x8 k1 = *(const bf16x8*)(KP + base + 8);
    float cs[16];
    float run = 0.0f;
#pragma unroll
    for (int x = 0; x < 8; ++x) {
      run += (float)q0[x] * (float)k0[x] * 0.125f;
      cs[x] = run;
    }
#pragma unroll
    for (int x = 0; x < 8; ++x) {
      run += (float)q1[x] * (float)k1[x] * 0.125f;
      cs[8 + x] = run;
    }
    float t1 = __shfl_up(run, 1, 4);
    float t2 = __shfl_up(run, 2, 4);
    float t3 = __shfl_up(run, 3, 4);
    float off = 0.0f;
    if (seg > 0) off += t1;
    if (seg > 1) off += t2;
    if (seg > 2) off += t3;
    float4* dst = (float4*)&csl[i][seg * 16];
#pragma unroll
    for (int x4 = 0; x4 < 4; ++x4)
      dst[x4] = make_float4(cs[4 * x4] + off, cs[4 * x4 + 1] + off,
                            cs[4 * x4 + 2] + off, cs[4 * x4 + 3] + off);
  }
  __syncthreads();

  // phase B: wei for j<80, softmax max/sum (tail logit = 0, count 944)
  {
    int i = t >> 2, jg = t & 3;
    float wloc[20];
    float mx = 0.0f;  // includes tail's wei=0
#pragma unroll
    for (int q = 0; q < 20; ++q) {
      int j = jg + 4 * q;
      int s = j - 16; s = s < 0 ? 0 : s;
      int e = j + 16; e = e > 64 ? 64 : e;
      float w = csl[i][e - 1] - (s > 0 ? csl[i][s - 1] : 0.0f);
      wloc[q] = w;
      mx = fmaxf(mx, w);
    }
    mx = fmaxf(mx, __shfl_xor(mx, 1, 64));
    mx = fmaxf(mx, __shfl_xor(mx, 2, 64));
    float sum = 0.0f;
#pragma unroll
    for (int q = 0; q < 20; ++q) {
      float e_ = __expf(wloc[q] - mx);
      wlb[i][jg + 4 * q] = __float2bfloat16(e_);
      sum += e_;
    }
#pragma unroll
    for (int q = 0; q < 4; ++q)      // zero pad j = 80..95
      wlb[i][80 + jg + 4 * q] = __float2bfloat16(0.0f);
    sum += __shfl_xor(sum, 1, 64);
    sum += __shfl_xor(sum, 2, 64);
    float tw = __expf(-mx);
    sum += 944.0f * tw;
    if (jg == 0) { scl[i] = 1.0f / sum; tlw[i] = tw / sum; }
  }
  __syncthreads();   // all csl reads done -> safe to overlay with vpt

  // phase C: stage vp^T[d][j] for j<80; zero-pad j=80..95
  for (int idx = t; idx < 80 * 64; idx += 256) {
    int j = idx >> 6, d = idx & 63;
    vpt[d][j] = VP[((size_t)(b * 1024 + j)) * 1024 + h * 64 + d];
  }
  for (int idx = t; idx < 64 * 16; idx += 256) {
    int d = idx >> 4, j = 80 + (idx & 15);
    vpt[d][j] = __float2bfloat16(0.0f);
  }
  __syncthreads();

  // phase D: O[i][d] = sum_j wl[i][j] * vpt[d][j] via MFMA (M=64,N=64,K=96)
  {
    const int mh = (wv >> 1) * 32, nh = (wv & 1) * 32;
    const int mrow = lane & 15, kq = lane >> 4;
    f32x4 acc[2][2] = {};
#pragma unroll
    for (int k0 = 0; k0 < 96; k0 += 32) {
      bf16x8 af[2], bf[2];
#pragma unroll
      for (int mi = 0; mi < 2; ++mi)
        af[mi] = *(const bf16x8*)&wlb[mh + mi * 16 + mrow][k0 + kq * 8];
#pragma unroll
      for (int ni = 0; ni < 2; ++ni)
        bf[ni] = *(const bf16x8*)&vpt[nh + ni * 16 + mrow][k0 + kq * 8];
#pragma unroll
      for (int mi = 0; mi < 2; ++mi)
#pragma unroll
        for (int ni = 0; ni < 2; ++ni)
          acc[mi][ni] = __builtin_amdgcn_mfma_f32_16x16x32_bf16(af[mi], bf[ni], acc[mi][ni], 0, 0, 0);
    }
#pragma unroll
    for (int mi = 0; mi < 2; ++mi)
#pragma unroll
      for (int ni = 0; ni < 2; ++ni)
#pragma unroll
        for (int r = 0; r < 4; ++r) {
          int i = mh + mi * 16 + kq * 4 + r;
          int d = nh + ni * 16 + mrow;
          float o = acc[mi][ni][r] * scl[i] + tlw[i] * tail[d];
          OUTA[((size_t)(b * 1024 + i0 + i)) * 1024 + h * 64 + d] = __float2bfloat16(o);
        }
  }
}

// ---------------- launch ---------------------------------------------------
extern "C" void kernel_launch(void* const* d_in, const int* in_sizes, int n_in,
                              void* d_out, int out_size, void* d_ws, size_t ws_size,
                              hipStream_t stream)
{
  (void)in_sizes; (void)n_in; (void)out_size; (void)ws_size;
  const float* q  = (const float*)d_in[0];
  const float* k  = (const float*)d_in[1];
  const float* v  = (const float*)d_in[2];
  const float* Wq = (const float*)d_in[3];
  const float* Wk = (const float*)d_in[4];
  const float* Wv = (const float*)d_in[5];
  const float* Wp = (const float*)d_in[6];
  const float* bp = (const float*)d_in[7];

  char* ws = (char*)d_ws;
  __hip_bfloat16* qkv_bf = (__hip_bfloat16*)(ws);              // 24 MB (q,k,v bf16)
  __hip_bfloat16* w_bf   = (__hip_bfloat16*)(ws + 25165824);   // 8 MB (Wq,Wk,Wv,Wp)
  __hip_bfloat16* QKVp   = (__hip_bfloat16*)(ws + 33554432);   // 24 MB (qp,kp,vp bf16)
  __hip_bfloat16* OUTA   = (__hip_bfloat16*)(ws + 58720256);   // 8 MB
  float*          tails  = (float*)(ws + 67108864);            // 16 KB fp32
  float*          vsum   = (float*)(ws + 67108864 + 16384);    // 16 KB fp32
  float* out = (float*)d_out;

  cvt_kernel<<<dim3(16385), 256, 0, stream>>>(q, k, v, Wq, Wk, Wv, Wp,
      (ushort4*)qkv_bf, (ushort4*)w_bf, vsum);
  vsum_kernel<<<dim3(236), 256, 0, stream>>>(qkv_bf + (size_t)2 * 4194304, vsum);
  qkv_gemm_kernel<<<dim3(1096), 256, 0, stream>>>(qkv_bf, w_bf, QKVp, vsum, tails);
  attn_kernel<<<dim3(16, 16, 4), 256, 0, stream>>>(QKVp, QKVp + (size_t)4194304,
                                                   QKVp + (size_t)2 * 4194304, tails, OUTA);
  final_gemm_kernel<<<dim3(1024), 256, 0, stream>>>(OUTA, w_bf + (size_t)3 * 1048576,
                                                    out, bp);
}

// Round 4
// 188.615 us; speedup vs baseline: 1.1800x; 1.1396x over previous
//
#include <hip/hip_runtime.h>
#include <hip/hip_bf16.h>
#include <stdint.h>

// B=4, T=1024, C=1024, H=16, D=64, ks=16
// wei[b,h,i,j] = cs[i][e(j)] - cs[i][s(j)], s=clip(j-16,0,64), e=clip(j+16,0,64)
// => wei==0 for j>=80; softmax tail folds into one weight * tail-sum of vp.
// R12: coalesced tails GEMV. R10/R11 both pinned at ~71us because the 8 GEMV
//      blocks (lane-stride-4KB Wv reads, serial scalar vs loads) formed a
//      ~60us near-idle tail. New GEMV: wave-per-row coalesced reads + shuffle
//      reduction, placed at grid FRONT. GEMM mapping unchanged from R11.

typedef __bf16 bf16x8 __attribute__((ext_vector_type(8)));
typedef float f32x4 __attribute__((ext_vector_type(4)));

#define AS1(p) ((__attribute__((address_space(1))) void*)(p))
#define AS3(p) ((__attribute__((address_space(3))) void*)(p))

__device__ __forceinline__ float b2f(unsigned short h) {
  union { unsigned int u; float f; } x; x.u = ((unsigned int)h) << 16; return x.f;
}

// ---------------- fused fp32 -> bf16 convert (float4 per thread) ----------
// flat: idx<3M -> q,k,v (1M float4 each); else -> Wq,Wk,Wv,Wp (256K each).
// Block 16384 zeroes the 4096-float vsum buffer (consumer vsum_kernel is a
// later launch on the same stream).
__global__ __launch_bounds__(256) void cvt_kernel(
    const float* __restrict__ q, const float* __restrict__ k,
    const float* __restrict__ v, const float* __restrict__ Wq,
    const float* __restrict__ Wk, const float* __restrict__ Wv,
    const float* __restrict__ Wp,
    ushort4* __restrict__ qkv_bf, ushort4* __restrict__ w_bf,
    float* __restrict__ vsum)
{
  if (blockIdx.x == 16384) {
    float4* tz = (float4*)vsum;
    tz[threadIdx.x * 4 + 0] = make_float4(0.f, 0.f, 0.f, 0.f);
    tz[threadIdx.x * 4 + 1] = make_float4(0.f, 0.f, 0.f, 0.f);
    tz[threadIdx.x * 4 + 2] = make_float4(0.f, 0.f, 0.f, 0.f);
    tz[threadIdx.x * 4 + 3] = make_float4(0.f, 0.f, 0.f, 0.f);
    return;
  }
  int idx = blockIdx.x * 256 + threadIdx.x;
  const float* src; ushort4* dst; int i;
  if (idx < 3145728) {
    int which = idx >> 20; i = idx & 1048575;
    src = which == 0 ? q : which == 1 ? k : v;
    dst = qkv_bf + (size_t)which * 1048576 + i;
  } else {
    int w = idx - 3145728; int which = w >> 18; i = w & 262143;
    src = which == 0 ? Wq : which == 1 ? Wk : which == 2 ? Wv : Wp;
    dst = w_bf + w;
  }
  float4 val = ((const float4*)src)[i];
  union { ushort4 u; __hip_bfloat16 h[4]; } c;
  c.h[0] = __float2bfloat16(val.x); c.h[1] = __float2bfloat16(val.y);
  c.h[2] = __float2bfloat16(val.z); c.h[3] = __float2bfloat16(val.w);
  dst[0] = c.u;
}

// -------- vsum[b][c] = sum_{j>=80} v_bf[b,j,c]  (fp32 atomics) -------------
// 944 tail rows = 59 chunks x 16 rows; grid 236 = 4b x 59. Full unroll gives
// 16 independent ushort4 loads in flight per thread.
__global__ __launch_bounds__(256) void vsum_kernel(
    const __hip_bfloat16* __restrict__ Vbf, float* __restrict__ vsum)
{
  int b = blockIdx.x / 59, rc = blockIdx.x % 59;
  int c0 = threadIdx.x * 4;
  int j0 = 80 + rc * 16;
  const __hip_bfloat16* base = Vbf + ((size_t)(b * 1024 + j0)) * 1024 + c0;
  float s0 = 0.f, s1 = 0.f, s2 = 0.f, s3 = 0.f;
#pragma unroll
  for (int jj = 0; jj < 16; ++jj) {
    ushort4 u = *(const ushort4*)(base + (size_t)jj * 1024);
    s0 += b2f(u.x); s1 += b2f(u.y); s2 += b2f(u.z); s3 += b2f(u.w);
  }
  float* dst = vsum + b * 1024 + c0;
  atomicAdd(dst + 0, s0); atomicAdd(dst + 1, s1);
  atomicAdd(dst + 2, s2); atomicAdd(dst + 3, s3);
}

// ------- bf16 NT GEMM tile: 128 rows x 64 cols, K=1024, BK=64 -------------
// 24KB LDS; bf16 epilogue.
__device__ __forceinline__ void gemm128x64(
    const __hip_bfloat16* __restrict__ A, const __hip_bfloat16* __restrict__ Bw,
    __hip_bfloat16* __restrict__ C)
{
  const int N = 1024, K = 1024;
  __shared__ __align__(16) __hip_bfloat16 As[2][128 * 32];
  __shared__ __align__(16) __hip_bfloat16 Bs[2][64 * 32];
  const int t = threadIdx.x;
  const int wv = t >> 6, lane = t & 63;
  const int wRow = (wv >> 1) * 64, wCol = (wv & 1) * 32;
  const int mrow = lane & 15, kq = lane >> 4;

  f32x4 acc[4][2] = {};

  for (int k0 = 0; k0 < K; k0 += 64) {
    __syncthreads();
    // 24 chunks of 1024B per K-step: 16 A (2 halves x 8), 8 B (2 halves x 4)
#pragma unroll
    for (int tI = 0; tI < 6; ++tI) {
      int c = wv * 6 + tI;
      const __hip_bfloat16* gsrc;
      __hip_bfloat16* ldst;
      if (c < 16) {
        int half = c >> 3, ch = c & 7;
        int byteOff = ch * 1024 + lane * 16;
        gsrc = A + (size_t)(byteOff >> 6) * K + k0 + half * 32 + ((byteOff & 63) >> 1);
        ldst = &As[half][ch * 512];
      } else {
        int cb = c - 16; int half = cb >> 2, ch = cb & 3;
        int byteOff = ch * 1024 + lane * 16;
        gsrc = Bw + (size_t)(byteOff >> 6) * K + k0 + half * 32 + ((byteOff & 63) >> 1);
        ldst = &Bs[half][ch * 512];
      }
      __builtin_amdgcn_global_load_lds(AS1((void*)gsrc), AS3(ldst), 16, 0, 0);
    }
    __syncthreads();

#pragma unroll
    for (int half = 0; half < 2; ++half) {
      bf16x8 af[4], bf[2];
#pragma unroll
      for (int mi = 0; mi < 4; ++mi)
        af[mi] = *(const bf16x8*)&As[half][(wRow + mi * 16 + mrow) * 32 + kq * 8];
#pragma unroll
      for (int ni = 0; ni < 2; ++ni)
        bf[ni] = *(const bf16x8*)&Bs[half][(wCol + ni * 16 + mrow) * 32 + kq * 8];
#pragma unroll
      for (int mi = 0; mi < 4; ++mi)
#pragma unroll
        for (int ni = 0; ni < 2; ++ni)
          acc[mi][ni] = __builtin_amdgcn_mfma_f32_16x16x32_bf16(af[mi], bf[ni], acc[mi][ni], 0, 0, 0);
    }
  }

  // C/D layout: col = lane&15, row = (lane>>4)*4 + r   [m89-verified]
#pragma unroll
  for (int mi = 0; mi < 4; ++mi)
#pragma unroll
    for (int ni = 0; ni < 2; ++ni)
#pragma unroll
      for (int r = 0; r < 4; ++r) {
        int row = wRow + mi * 16 + kq * 4 + r;
        int col = wCol + ni * 16 + mrow;
        C[(size_t)row * N + col] = __float2bfloat16(acc[mi][ni][r]);
      }
}

// QKV: 1096 blocks.
//   [0,8):       tails GEMV (coalesced, wave-per-row) -- starts first, ~5us
//   [8,1032):    q,k at 128x64: z = g>>9, n = (g&511)>>5 (16), m = g&31 (32)
//   [1032,1096): v at 128x64, only rows [b*1024, b*1024+128)
__global__ __launch_bounds__(256) void qkv_gemm_kernel(
    const __hip_bfloat16* __restrict__ QKVbf, const __hip_bfloat16* __restrict__ Wbf,
    __hip_bfloat16* __restrict__ QKVp, const float* __restrict__ vsum,
    float* __restrict__ tails)
{
  int l = blockIdx.x;            // 0..1095
  if (l < 8) {
    // tails[b][c] = sum_k vsum[b][k] * Wv[c][k]
    // wave-per-row: lane reads Wv[c][lane*16..+15] (2KB contiguous per wave);
    // vs slices live in registers; 6-step shuffle reduction per b.
    const int lane = threadIdx.x & 63, wvv = threadIdx.x >> 6;
    float vs[4][16];
#pragma unroll
    for (int b = 0; b < 4; ++b) {
      const float4* srcv = (const float4*)(vsum + b * 1024 + lane * 16);
#pragma unroll
      for (int i = 0; i < 4; ++i) {
        float4 tv = srcv[i];
        vs[b][i * 4 + 0] = tv.x; vs[b][i * 4 + 1] = tv.y;
        vs[b][i * 4 + 2] = tv.z; vs[b][i * 4 + 3] = tv.w;
      }
    }
    const __hip_bfloat16* Wv = Wbf + (size_t)2 * 1048576;
    int c0 = l * 128 + wvv * 32;
    for (int r = 0; r < 32; ++r) {
      int c = c0 + r;
      const __hip_bfloat16* wrow = Wv + (size_t)c * 1024 + lane * 16;
      bf16x8 w0 = *(const bf16x8*)wrow;
      bf16x8 w1 = *(const bf16x8*)(wrow + 8);
      float p0 = 0.f, p1 = 0.f, p2 = 0.f, p3 = 0.f;
#pragma unroll
      for (int x = 0; x < 8; ++x) {
        float a = (float)w0[x], bq = (float)w1[x];
        p0 += a * vs[0][x] + bq * vs[0][8 + x];
        p1 += a * vs[1][x] + bq * vs[1][8 + x];
        p2 += a * vs[2][x] + bq * vs[2][8 + x];
        p3 += a * vs[3][x] + bq * vs[3][8 + x];
      }
#pragma unroll
      for (int off = 1; off < 64; off <<= 1) {
        p0 += __shfl_xor(p0, off, 64);
        p1 += __shfl_xor(p1, off, 64);
        p2 += __shfl_xor(p2, off, 64);
        p3 += __shfl_xor(p3, off, 64);
      }
      if (lane == 0) {
        tails[c] = p0; tails[1024 + c] = p1;
        tails[2048 + c] = p2; tails[3072 + c] = p3;
      }
    }
    return;
  }
  int g = l - 8;
  int z, m, n;
  if (g < 1024) { z = g >> 9; int r = g & 511; n = r >> 5; m = r & 31; }
  else          { z = 2; int r = g - 1024; m = (r >> 4) * 8; n = r & 15; }
  gemm128x64(
      QKVbf + (size_t)z * 4194304 + (size_t)m * 131072,
      Wbf + (size_t)z * 1048576 + (size_t)n * 65536,
      QKVp + (size_t)z * 4194304 + (size_t)m * 131072 + n * 64);
}

// ------- final GEMM: 64x64 tiles, 1024 blocks (4/CU), BK=64 ---------------
__global__ __launch_bounds__(256) void final_gemm_kernel(
    const __hip_bfloat16* __restrict__ Abf, const __hip_bfloat16* __restrict__ Wpbf,
    float* __restrict__ Out, const float* __restrict__ biasAll)
{
  const int N = 1024, K = 1024;
  int l = blockIdx.x;            // 0..1023
  int m = l & 63, n = l >> 6;    // m fastest -> XCD A-strip reuse
  const __hip_bfloat16* A = Abf + (size_t)m * 65536;      // 64 rows
  const __hip_bfloat16* Bw = Wpbf + (size_t)n * 65536;    // 64 rows
  float* C = Out + (size_t)m * 65536 + n * 64;
  const float* bias = biasAll + n * 64;

  __shared__ __align__(16) __hip_bfloat16 As[2][64 * 32];
  __shared__ __align__(16) __hip_bfloat16 Bs[2][64 * 32];
  const int t = threadIdx.x;
  const int wv = t >> 6, lane = t & 63;
  const int wRow = (wv >> 1) * 32, wCol = (wv & 1) * 32;
  const int mrow = lane & 15, kq = lane >> 4;

  f32x4 acc[2][2] = {};

  for (int k0 = 0; k0 < K; k0 += 64) {
    __syncthreads();
#pragma unroll
    for (int tI = 0; tI < 4; ++tI) {
      int c = wv * 4 + tI;                     // 0..15 chunks of 1024B
      int half, ch;
      const __hip_bfloat16* gsrc;
      __hip_bfloat16* ldst;
      if (c < 8) { half = c >> 2; ch = c & 3;
        int byteOff = ch * 1024 + lane * 16;
        gsrc = A + (size_t)(byteOff >> 6) * K + k0 + half * 32 + ((byteOff & 63) >> 1);
        ldst = &As[half][ch * 512];
      } else { int cb = c - 8; half = cb >> 2; ch = cb & 3;
        int byteOff = ch * 1024 + lane * 16;
        gsrc = Bw + (size_t)(byteOff >> 6) * K + k0 + half * 32 + ((byteOff & 63) >> 1);
        ldst = &Bs[half][ch * 512];
      }
      __builtin_amdgcn_global_load_lds(AS1((void*)gsrc), AS3(ldst), 16, 0, 0);
    }
    __syncthreads();

#pragma unroll
    for (int half = 0; half < 2; ++half) {
      bf16x8 af[2], bf[2];
#pragma unroll
      for (int mi = 0; mi < 2; ++mi)
        af[mi] = *(const bf16x8*)&As[half][(wRow + mi * 16 + mrow) * 32 + kq * 8];
#pragma unroll
      for (int ni = 0; ni < 2; ++ni)
        bf[ni] = *(const bf16x8*)&Bs[half][(wCol + ni * 16 + mrow) * 32 + kq * 8];
#pragma unroll
      for (int mi = 0; mi < 2; ++mi)
#pragma unroll
        for (int ni = 0; ni < 2; ++ni)
          acc[mi][ni] = __builtin_amdgcn_mfma_f32_16x16x32_bf16(af[mi], bf[ni], acc[mi][ni], 0, 0, 0);
    }
  }

#pragma unroll
  for (int mi = 0; mi < 2; ++mi)
#pragma unroll
    for (int ni = 0; ni < 2; ++ni)
#pragma unroll
      for (int r = 0; r < 4; ++r) {
        int row = wRow + mi * 16 + kq * 4 + r;
        int col = wCol + ni * 16 + mrow;
        // out is never re-read on device: bypass L2 with non-temporal store
        __builtin_nontemporal_store(acc[mi][ni][r] + bias[col],
                                    &C[(size_t)row * N + col]);
      }
}

// ---------------- attention: per (b,h, 64-row i-tile) ---------------------
// LDS: bufA holds csl (f32 64x68) during phases A/B, then vpt (bf16 64x104)
// for phase D. wlb + scalars separate. ~30.4 KB total -> 4 blocks/CU.
__global__ __launch_bounds__(256) void attn_kernel(
    const __hip_bfloat16* __restrict__ QP, const __hip_bfloat16* __restrict__ KP,
    const __hip_bfloat16* __restrict__ VP, const float* __restrict__ tails,
    __hip_bfloat16* __restrict__ OUTA)
{
  const int b = blockIdx.z, h = blockIdx.y, i0 = blockIdx.x * 64;
  const int t = threadIdx.x, lane = t & 63, wv = t >> 6;

  __shared__ __align__(16) char bufA[64 * 68 * 4];      // csl f32 / vpt bf16 overlay
  float (*csl)[68] = (float(*)[68])bufA;                // inclusive cumsum
  __hip_bfloat16 (*vpt)[104] = (__hip_bfloat16(*)[104])bufA;  // vp^T B-operand
  __shared__ __align__(16) __hip_bfloat16 wlb[64][96];  // exp(wei-m), A-operand [i][j]
  __shared__ float scl[64], tlw[64], tail[64];

  if (t < 64) tail[t] = tails[(size_t)b * 1024 + h * 64 + t];

  // phase A: p = qp*kp/8, inclusive cumsum over d.
  {
    const int i = t >> 2, seg = t & 3;
    const size_t base = ((size_t)(b * 1024 + i0 + i)) * 1024 + h * 64 + seg * 16;
    bf16x8 q0 = *(const bf16x8*)(QP + base);
    bf16x8 q1 = *(const bf16x8*)(QP + base + 8);
    bf16x8 k0 = *(const bf16x8*)(KP + base);
    bf16x8 k1 = *(const bf16x8*)(KP + base + 8);
    float cs[16];
    float run = 0.0f;
#pragma unroll
    for (int x = 0; x < 8; ++x) {
      run += (float)q0[x] * (float)k0[x] * 0.125f;
      cs[x] = run;
    }
#pragma unroll
    for (int x = 0; x < 8; ++x) {
      run += (float)q1[x] * (float)k1[x] * 0.125f;
      cs[8 + x] = run;
    }
    float t1 = __shfl_up(run, 1, 4);
    float t2 = __shfl_up(run, 2, 4);
    float t3 = __shfl_up(run, 3, 4);
    float off = 0.0f;
    if (seg > 0) off += t1;
    if (seg > 1) off += t2;
    if (seg > 2) off += t3;
    float4* dst = (float4*)&csl[i][seg * 16];
#pragma unroll
    for (int x4 = 0; x4 < 4; ++x4)
      dst[x4] = make_float4(cs[4 * x4] + off, cs[4 * x4 + 1] + off,
                            cs[4 * x4 + 2] + off, cs[4 * x4 + 3] + off);
  }
  __syncthreads();

  // phase B: wei for j<80, softmax max/sum (tail logit = 0, count 944)
  {
    int i = t >> 2, jg = t & 3;
    float wloc[20];
    float mx = 0.0f;  // includes tail's wei=0
#pragma unroll
    for (int q = 0; q < 20; ++q) {
      int j = jg + 4 * q;
      int s = j - 16; s = s < 0 ? 0 : s;
      int e = j + 16; e = e > 64 ? 64 : e;
      float w = csl[i][e - 1] - (s > 0 ? csl[i][s - 1] : 0.0f);
      wloc[q] = w;
      mx = fmaxf(mx, w);
    }
    mx = fmaxf(mx, __shfl_xor(mx, 1, 64));
    mx = fmaxf(mx, __shfl_xor(mx, 2, 64));
    float sum = 0.0f;
#pragma unroll
    for (int q = 0; q < 20; ++q) {
      float e_ = __expf(wloc[q] - mx);
      wlb[i][jg + 4 * q] = __float2bfloat16(e_);
      sum += e_;
    }
#pragma unroll
    for (int q = 0; q < 4; ++q)      // zero pad j = 80..95
      wlb[i][80 + jg + 4 * q] = __float2bfloat16(0.0f);
    sum += __shfl_xor(sum, 1, 64);
    sum += __shfl_xor(sum, 2, 64);
    float tw = __expf(-mx);
    sum += 944.0f * tw;
    if (jg == 0) { scl[i] = 1.0f / sum; tlw[i] = tw / sum; }
  }
  __syncthreads();   // all csl reads done -> safe to overlay with vpt

  // phase C: stage vp^T[d][j] for j<80; zero-pad j=80..95
  for (int idx = t; idx < 80 * 64; idx += 256) {
    int j = idx >> 6, d = idx & 63;
    vpt[d][j] = VP[((size_t)(b * 1024 + j)) * 1024 + h * 64 + d];
  }
  for (int idx = t; idx < 64 * 16; idx += 256) {
    int d = idx >> 4, j = 80 + (idx & 15);
    vpt[d][j] = __float2bfloat16(0.0f);
  }
  __syncthreads();

  // phase D: O[i][d] = sum_j wl[i][j] * vpt[d][j] via MFMA (M=64,N=64,K=96)
  {
    const int mh = (wv >> 1) * 32, nh = (wv & 1) * 32;
    const int mrow = lane & 15, kq = lane >> 4;
    f32x4 acc[2][2] = {};
#pragma unroll
    for (int k0 = 0; k0 < 96; k0 += 32) {
      bf16x8 af[2], bf[2];
#pragma unroll
      for (int mi = 0; mi < 2; ++mi)
        af[mi] = *(const bf16x8*)&wlb[mh + mi * 16 + mrow][k0 + kq * 8];
#pragma unroll
      for (int ni = 0; ni < 2; ++ni)
        bf[ni] = *(const bf16x8*)&vpt[nh + ni * 16 + mrow][k0 + kq * 8];
#pragma unroll
      for (int mi = 0; mi < 2; ++mi)
#pragma unroll
        for (int ni = 0; ni < 2; ++ni)
          acc[mi][ni] = __builtin_amdgcn_mfma_f32_16x16x32_bf16(af[mi], bf[ni], acc[mi][ni], 0, 0, 0);
    }
#pragma unroll
    for (int mi = 0; mi < 2; ++mi)
#pragma unroll
      for (int ni = 0; ni < 2; ++ni)
#pragma unroll
        for (int r = 0; r < 4; ++r) {
          int i = mh + mi * 16 + kq * 4 + r;
          int d = nh + ni * 16 + mrow;
          float o = acc[mi][ni][r] * scl[i] + tlw[i] * tail[d];
          OUTA[((size_t)(b * 1024 + i0 + i)) * 1024 + h * 64 + d] = __float2bfloat16(o);
        }
  }
}

// ---------------- launch ---------------------------------------------------
extern "C" void kernel_launch(void* const* d_in, const int* in_sizes, int n_in,
                              void* d_out, int out_size, void* d_ws, size_t ws_size,
                              hipStream_t stream)
{
  (void)in_sizes; (void)n_in; (void)out_size; (void)ws_size;
  const float* q  = (const float*)d_in[0];
  const float* k  = (const float*)d_in[1];
  const float* v  = (const float*)d_in[2];
  const float* Wq = (const float*)d_in[3];
  const float* Wk = (const float*)d_in[4];
  const float* Wv = (const float*)d_in[5];
  const float* Wp = (const float*)d_in[6];
  const float* bp = (const float*)d_in[7];

  char* ws = (char*)d_ws;
  __hip_bfloat16* qkv_bf = (__hip_bfloat16*)(ws);              // 24 MB (q,k,v bf16)
  __hip_bfloat16* w_bf   = (__hip_bfloat16*)(ws + 25165824);   // 8 MB (Wq,Wk,Wv,Wp)
  __hip_bfloat16* QKVp   = (__hip_bfloat16*)(ws + 33554432);   // 24 MB (qp,kp,vp bf16)
  __hip_bfloat16* OUTA   = (__hip_bfloat16*)(ws + 58720256);   // 8 MB
  float*          tails  = (float*)(ws + 67108864);            // 16 KB fp32
  float*          vsum   = (float*)(ws + 67108864 + 16384);    // 16 KB fp32
  float* out = (float*)d_out;

  cvt_kernel<<<dim3(16385), 256, 0, stream>>>(q, k, v, Wq, Wk, Wv, Wp,
      (ushort4*)qkv_bf, (ushort4*)w_bf, vsum);
  vsum_kernel<<<dim3(236), 256, 0, stream>>>(qkv_bf + (size_t)2 * 4194304, vsum);
  qkv_gemm_kernel<<<dim3(1096), 256, 0, stream>>>(qkv_bf, w_bf, QKVp, vsum, tails);
  attn_kernel<<<dim3(16, 16, 4), 256, 0, stream>>>(QKVp, QKVp + (size_t)4194304,
                                                   QKVp + (size_t)2 * 4194304, tails, OUTA);
  final_gemm_kernel<<<dim3(1024), 256, 0, stream>>>(OUTA, w_bf + (size_t)3 * 1048576,
                                                    out, bp);
}